// Round 4
// baseline (211.794 us; speedup 1.0000x reference)
//
#include <hip/hip_runtime.h>

#define H  256
#define W  256
#define S  4
#define OH (H * S)
#define OW (W * S)

typedef float vfloat4 __attribute__((ext_vector_type(4)));

// Block = one 4-row input slab x full 256-col width x one (n,c).
// Stage the 7 needed input rows in LDS with coalesced loads, then each
// thread produces a 16(h) x 4(w) output tile via 16 nontemporal float4
// stores (each store = 64 lanes x 16 B = 1 KiB contiguous).
__global__ __launch_bounds__(256) void bicubic_up4(
    const float* __restrict__ x, const float* __restrict__ kern,
    float* __restrict__ out)
{
    __shared__ float sm[7][W];

    const int iw  = threadIdx.x;        // input column 0..255
    const int ihb = blockIdx.x * 4;     // first input row of this slab
    const int nc  = blockIdx.y;         // n*c 0..47

    // 16 filter taps (4 phases x 4 taps) — uniform address, scalarized
    float kk[16];
#pragma unroll
    for (int i = 0; i < 16; ++i) kk[i] = kern[i];

    const float* __restrict__ xp = x + (size_t)nc * (H * W);

    // stage rows ihb-1 .. ihb+5 (replicate clamp), fully coalesced
#pragma unroll
    for (int t = 0; t < 7; ++t) {
        int r = ihb - 1 + t;
        r = r < 0 ? 0 : (r > H - 1 ? H - 1 : r);
        sm[t][iw] = xp[r * W + iw];
    }
    __syncthreads();

    // horizontal taps: cols iw-1 .. iw+2 (replicate clamp)
    const int c0 = max(iw - 1, 0);
    const int c2 = min(iw + 1, W - 1);
    const int c3 = min(iw + 2, W - 1);

    float p[7][4];
#pragma unroll
    for (int t = 0; t < 7; ++t) {
        p[t][0] = sm[t][c0];
        p[t][1] = sm[t][iw];
        p[t][2] = sm[t][c2];
        p[t][3] = sm[t][c3];
    }

    float* __restrict__ obase =
        out + ((size_t)nc * OH + (size_t)ihb * S) * OW + (size_t)iw * S;

#pragma unroll
    for (int q = 0; q < 4; ++q) {          // input row within the slab
#pragma unroll
        for (int kv = 0; kv < 4; ++kv) {   // vertical sub-pixel phase
            const float w0 = kk[kv * 4 + 0];
            const float w1 = kk[kv * 4 + 1];
            const float w2 = kk[kv * 4 + 2];
            const float w3 = kk[kv * 4 + 3];
            const float v0 = p[q][0]*w0 + p[q+1][0]*w1 + p[q+2][0]*w2 + p[q+3][0]*w3;
            const float v1 = p[q][1]*w0 + p[q+1][1]*w1 + p[q+2][1]*w2 + p[q+3][1]*w3;
            const float v2 = p[q][2]*w0 + p[q+1][2]*w1 + p[q+2][2]*w2 + p[q+3][2]*w3;
            const float v3 = p[q][3]*w0 + p[q+1][3]*w1 + p[q+2][3]*w2 + p[q+3][3]*w3;
            vfloat4 o;
            o.x = v0*kk[0]  + v1*kk[1]  + v2*kk[2]  + v3*kk[3];
            o.y = v0*kk[4]  + v1*kk[5]  + v2*kk[6]  + v3*kk[7];
            o.z = v0*kk[8]  + v1*kk[9]  + v2*kk[10] + v3*kk[11];
            o.w = v0*kk[12] + v1*kk[13] + v2*kk[14] + v3*kk[15];
            __builtin_nontemporal_store(
                o, reinterpret_cast<vfloat4*>(obase + ((size_t)q * S + kv) * OW));
        }
    }
}

extern "C" void kernel_launch(void* const* d_in, const int* in_sizes, int n_in,
                              void* d_out, int out_size, void* d_ws, size_t ws_size,
                              hipStream_t stream) {
    const float* x    = (const float*)d_in[0];
    const float* kern = (const float*)d_in[1];
    float* out        = (float*)d_out;

    dim3 grid(H / 4, 16 * 3);   // 64 x 48 blocks
    dim3 block(256);            // one thread per input column
    bicubic_up4<<<grid, block, 0, stream>>>(x, kern, out);
}